// Round 4
// baseline (34171.674 us; speedup 1.0000x reference)
//
#include <hip/hip_runtime.h>
#include <hip/hip_fp16.h>
#include <cmath>

// Problem constants (reference: B=256, T=512, IN=64, R=2048)
constexpr int kB  = 256;
constexpr int kT  = 512;
constexpr int kIN = 64;
constexpr int kR  = 2048;

constexpr int kBlocks = 256;   // 64 n-bands x 4 m-bands -> 1 block/CU, all resident
constexpr int BN = 32;         // n per block (W-band in registers)
constexpr int BM = 64;         // batches per block
constexpr int CH  = 256;       // k per staged s-chunk
constexpr int NCH = kR / CH;   // 8 chunks
constexpr int SST = CH + 8;    // ss row stride (halfs) = 264 -> uniform banks
constexpr int PFS = 36;        // partial-scratch row stride (words): uniform banks, 16B rows

typedef _Float16 f16x8 __attribute__((ext_vector_type(8)));
typedef float    f32x4 __attribute__((ext_vector_type(4)));
typedef unsigned long long u64;

#define MFMA16(a, b, c) __builtin_amdgcn_mfma_f32_16x16x32_f16((a), (b), (c), 0, 0, 0)

__device__ __forceinline__ f16x8 cvt8(float4 a, float4 b) {
    f16x8 v;
    v[0] = (_Float16)a.x; v[1] = (_Float16)a.y; v[2] = (_Float16)a.z; v[3] = (_Float16)a.w;
    v[4] = (_Float16)b.x; v[5] = (_Float16)b.y; v[6] = (_Float16)b.z; v[7] = (_Float16)b.w;
    return v;
}

// Persistent ESN: all 512 steps in one launch. Block = 64 batches x 32 units,
// W-band in VGPR/AGPR frags (HBM-read once). Cross-step coherence via
// release-fence (L2 writeback) -> counter -> relaxed spin -> acquire-fence
// (L1/L2 invalidate) -> plain cached coalesced loads. Double-buffered LDS
// s-chunks, 1 barrier/chunk.
__global__ __launch_bounds__(512, 2) void esn_persist(
    const float* __restrict__ X,     // [B, T, IN]
    const float* __restrict__ Win,   // [R, IN]
    const float* __restrict__ W,     // [R, R]
    float* __restrict__ out,         // [B, R]
    _Float16* __restrict__ sbuf0,
    _Float16* __restrict__ sbuf1,
    unsigned int* __restrict__ ctr)
{
    // 2 x 33792 B = 67584 B; fp32 partial scratch [4][64][36] (36864 B) aliases it
    __shared__ __align__(16) _Float16 ss[2][64 * SST];

    const int tid  = threadIdx.x;
    const int wave = tid >> 6, lane = tid & 63;
    const int quad = lane >> 4, l16 = lane & 15;
    const int mh = wave >> 2;        // m-half: rows [mh*32, mh*32+32)
    const int q  = wave & 3;         // k-phase: kk ≡ q (mod 4)
    const int n0 = (blockIdx.x & 63) * BN;
    const int m0 = (blockIdx.x >> 6) * BM;

    // ---- one-time: W-band -> register B-frags (f16) ----
    // wfrag[h][2c+half] = W[n0+h*16+l16][kk*32 + quad*8 + j], kk = 8c + 4*half + q
    f16x8 wfrag[2][2 * NCH];
    #pragma unroll
    for (int h = 0; h < 2; ++h) {
        const float* wrow = W + (size_t)(n0 + h * 16 + l16) * kR;
        #pragma unroll
        for (int kki = 0; kki < 2 * NCH; ++kki) {
            const int kk = (kki >> 1) * 8 + (kki & 1) * 4 + q;
            const float* p = wrow + kk * 32 + quad * 8;
            wfrag[h][kki] = cvt8(*(const float4*)p, *(const float4*)(p + 4));
        }
    }
    f16x8 winfrag[2] = {};
    if (q < 2) {
        #pragma unroll
        for (int h = 0; h < 2; ++h) {
            const float* p = Win + (size_t)(n0 + h * 16 + l16) * kIN + q * 32 + quad * 8;
            winfrag[h] = cvt8(*(const float4*)p, *(const float4*)(p + 4));
        }
    }

    // s staging geometry: 4 rounds x 512 threads x 8 halfs (16 B) per chunk
    const int srow0 = tid >> 5;            // 0..15, +16 per round
    const int sc8   = (tid & 31) * 8;      // col within chunk (halfs)
    const size_t sgbase = (size_t)(m0 + srow0) * kR + sc8;

    // LDS byte offsets for MFMA A-frag reads (rows in batch, cols in k)
    const int ldsA0 = ((2 * mh + 0) * 16 + l16) * SST;
    const int ldsA1 = ((2 * mh + 1) * 16 + l16) * SST;

    float* pf = (float*)ss;  // [4][64][PFS] fp32 partial scratch

    #pragma unroll 1
    for (int t = 0; t < kT; ++t) {
        f32x4 acc[2][2] = {};

        // ---- input term, A-frags straight from global X (1x coverage) ----
        if (q < 2) {
            #pragma unroll
            for (int i = 0; i < 2; ++i) {
                const float* xp = X + ((size_t)(m0 + (2 * mh + i) * 16 + l16) * kT + t) * kIN
                                + q * 32 + quad * 8;
                f16x8 a = cvt8(*(const float4*)xp, *(const float4*)(xp + 4));
                acc[i][0] = MFMA16(a, winfrag[0], acc[i][0]);
                acc[i][1] = MFMA16(a, winfrag[1], acc[i][1]);
            }
        }

        // ---- recurrent term over s_{t-1} ----
        if (t > 0) {
            const _Float16* sprev = (t & 1) ? sbuf0 : sbuf1;
            if (tid == 0) {
                const unsigned int need = (unsigned int)kBlocks * (unsigned int)t;
                while (__hip_atomic_load(ctr, __ATOMIC_RELAXED, __HIP_MEMORY_SCOPE_AGENT) < need)
                    __builtin_amdgcn_s_sleep(1);
            }
            __syncthreads();
            // make other XCDs' s-stores visible: invalidate L1/L2, then cached loads
            __builtin_amdgcn_fence(__ATOMIC_ACQUIRE, "agent");

            // preload chunk 0
            #pragma unroll
            for (int r = 0; r < 4; ++r) {
                f16x8 v = *(const f16x8*)(sprev + sgbase + (size_t)(16 * r) * kR);
                *(f16x8*)&ss[0][(srow0 + 16 * r) * SST + sc8] = v;
            }
            __syncthreads();

            #pragma unroll
            for (int c = 0; c < NCH; ++c) {
                f16x8 pre[4];
                if (c + 1 < NCH) {
                    #pragma unroll
                    for (int r = 0; r < 4; ++r)
                        pre[r] = *(const f16x8*)(sprev + sgbase + (size_t)(16 * r) * kR
                                                 + (c + 1) * CH);
                }
                const _Float16* buf = ss[c & 1];
                #pragma unroll
                for (int half = 0; half < 2; ++half) {
                    const int kloc = q * 32 + half * 128 + quad * 8;
                    f16x8 av0 = *(const f16x8*)&buf[ldsA0 + kloc];
                    f16x8 av1 = *(const f16x8*)&buf[ldsA1 + kloc];
                    acc[0][0] = MFMA16(av0, wfrag[0][2 * c + half], acc[0][0]);
                    acc[0][1] = MFMA16(av0, wfrag[1][2 * c + half], acc[0][1]);
                    acc[1][0] = MFMA16(av1, wfrag[0][2 * c + half], acc[1][0]);
                    acc[1][1] = MFMA16(av1, wfrag[1][2 * c + half], acc[1][1]);
                }
                if (c + 1 < NCH) {
                    _Float16* nbuf = ss[(c + 1) & 1];
                    #pragma unroll
                    for (int r = 0; r < 4; ++r)
                        *(f16x8*)&nbuf[(srow0 + 16 * r) * SST + sc8] = pre[r];
                }
                __syncthreads();  // next iter reads the buffer just filled
            }
        }

        // ---- reduce 4 k-phase partials through LDS, tanh, store ----
        // pf stride 36 words: quads hit distinct banks; rows 16B-aligned.
        #pragma unroll
        for (int i = 0; i < 2; ++i)
            #pragma unroll
            for (int h = 0; h < 2; ++h)
                #pragma unroll
                for (int r = 0; r < 4; ++r)
                    pf[q * 64 * PFS + (mh * 32 + i * 16 + quad * 4 + r) * PFS + h * 16 + l16]
                        = acc[i][h][r];
        __syncthreads();

        const int ml = tid >> 3, nl4 = (tid & 7) * 4;
        f32x4 v0 = *(const f32x4*)&pf[0 * 64 * PFS + ml * PFS + nl4];
        f32x4 v1 = *(const f32x4*)&pf[1 * 64 * PFS + ml * PFS + nl4];
        f32x4 v2 = *(const f32x4*)&pf[2 * 64 * PFS + ml * PFS + nl4];
        f32x4 v3 = *(const f32x4*)&pf[3 * 64 * PFS + ml * PFS + nl4];
        float o0 = tanhf(v0[0] + v1[0] + v2[0] + v3[0]);
        float o1 = tanhf(v0[1] + v1[1] + v2[1] + v3[1]);
        float o2 = tanhf(v0[2] + v1[2] + v2[2] + v3[2]);
        float o3 = tanhf(v0[3] + v1[3] + v2[3] + v3[3]);

        if (t < kT - 1) {
            _Float16* sout = (t & 1) ? sbuf1 : sbuf0;
            union { u64 u; _Float16 h[4]; } pk;
            pk.h[0] = (_Float16)o0; pk.h[1] = (_Float16)o1;
            pk.h[2] = (_Float16)o2; pk.h[3] = (_Float16)o3;
            *(u64*)(sout + (size_t)(m0 + ml) * kR + n0 + nl4) = pk.u;  // plain store
            // flush this thread's store to the coherence point (L2 writeback)
            __builtin_amdgcn_fence(__ATOMIC_RELEASE, "agent");
            __syncthreads();   // all waves flushed; also guards pf/ss reuse next step
            if (tid == 0)
                __hip_atomic_fetch_add(ctr, 1u, __ATOMIC_RELEASE, __HIP_MEMORY_SCOPE_AGENT);
        } else {
            float4 o; o.x = o0; o.y = o1; o.z = o2; o.w = o3;
            *(float4*)(out + (size_t)(m0 + ml) * kR + n0 + nl4) = o;
        }
    }
}

extern "C" void kernel_launch(void* const* d_in, const int* in_sizes, int n_in,
                              void* d_out, int out_size, void* d_ws, size_t ws_size,
                              hipStream_t stream)
{
    const float* X   = (const float*)d_in[0];  // [B, T, IN]
    const float* Win = (const float*)d_in[1];  // [R, IN]
    const float* W   = (const float*)d_in[2];  // [R, R]
    float* out = (float*)d_out;                // [B, R]

    char* ws = (char*)d_ws;
    _Float16* s0 = (_Float16*)ws;                                  // 1 MB
    _Float16* s1 = (_Float16*)(ws + (size_t)kB * kR * 2);          // 1 MB
    unsigned int* ctr = (unsigned int*)(ws + 2 * (size_t)kB * kR * 2);

    hipMemsetAsync(ctr, 0, sizeof(unsigned int), stream);
    esn_persist<<<kBlocks, 512, 0, stream>>>(X, Win, W, out, s0, s1, ctr);
}

// Round 5
// 6461.466 us; speedup vs baseline: 5.2885x; 5.2885x over previous
//
#include <hip/hip_runtime.h>
#include <hip/hip_fp16.h>
#include <cmath>

// Problem constants (reference: B=256, T=512, IN=64, R=2048)
constexpr int kB  = 256;
constexpr int kT  = 512;
constexpr int kIN = 64;
constexpr int kR  = 2048;

constexpr int kBlocks = 256;   // 64 n-bands x 4 m-bands -> 1 block/CU, all resident
constexpr int BN = 32;         // n per block (W-band in registers)
constexpr int BM = 64;         // batches per block
constexpr int CH  = 256;       // k per staged s-chunk
constexpr int NCH = kR / CH;   // 8 chunks
constexpr int SST = CH + 8;    // ss row stride (halfs) = 264 -> uniform banks
constexpr int PFS = 36;        // partial-scratch row stride (words)

typedef _Float16 f16x8 __attribute__((ext_vector_type(8)));
typedef float    f32x4 __attribute__((ext_vector_type(4)));
typedef unsigned long long u64;

#define MFMA16(a, b, c) __builtin_amdgcn_mfma_f32_16x16x32_f16((a), (b), (c), 0, 0, 0)

__device__ __forceinline__ f16x8 cvt8(float4 a, float4 b) {
    f16x8 v;
    v[0] = (_Float16)a.x; v[1] = (_Float16)a.y; v[2] = (_Float16)a.z; v[3] = (_Float16)a.w;
    v[4] = (_Float16)b.x; v[5] = (_Float16)b.y; v[6] = (_Float16)b.z; v[7] = (_Float16)b.w;
    return v;
}

// Persistent ESN: all 512 steps in one launch. Block = 64 batches x 32 units,
// W-band register-resident (HBM-read once).
// Coherence protocol (cache-op-minimal):
//   producers: scoped-atomic u64 s-stores (write-through to L3, NO wbl2)
//              -> s_waitcnt vmcnt(0) -> __syncthreads -> relaxed fetch_add.
//   consumers: wave0 spins relaxed, then ONE acquire fence (buffer_inv)
//              per block per step -> __syncthreads -> plain cached loads.
// r3/r4 ran wbl2/inv in EVERY wave every step (256 cache ops/XCD/step) —
// that serialization is the hypothesized 65 us/step; here it is 32/XCD/step
// inv-only.
__global__ __launch_bounds__(512, 2) void esn_persist(
    const float* __restrict__ X,     // [B, T, IN]
    const float* __restrict__ Win,   // [R, IN]
    const float* __restrict__ W,     // [R, R]
    float* __restrict__ out,         // [B, R]
    _Float16* __restrict__ sbuf0,
    _Float16* __restrict__ sbuf1,
    unsigned int* __restrict__ ctr)
{
    // 2 x 33792 B = 67584 B; fp32 partial scratch [4][64][36] aliases it
    __shared__ __align__(16) _Float16 ss[2][64 * SST];

    const int tid  = threadIdx.x;
    const int wave = tid >> 6, lane = tid & 63;
    const int quad = lane >> 4, l16 = lane & 15;
    const int mh = wave >> 2;        // m-half: rows [mh*32, mh*32+32)
    const int q  = wave & 3;         // k-phase: kk ≡ q (mod 4)
    const int n0 = (blockIdx.x & 63) * BN;
    const int m0 = (blockIdx.x >> 6) * BM;

    // ---- one-time: W-band -> register B-frags (f16) ----
    // wfrag[h][2c+half] = W[n0+h*16+l16][kk*32 + quad*8 + j], kk = 8c + 4*half + q
    f16x8 wfrag[2][2 * NCH];
    #pragma unroll
    for (int h = 0; h < 2; ++h) {
        const float* wrow = W + (size_t)(n0 + h * 16 + l16) * kR;
        #pragma unroll
        for (int kki = 0; kki < 2 * NCH; ++kki) {
            const int kk = (kki >> 1) * 8 + (kki & 1) * 4 + q;
            const float* p = wrow + kk * 32 + quad * 8;
            wfrag[h][kki] = cvt8(*(const float4*)p, *(const float4*)(p + 4));
        }
    }
    f16x8 winfrag[2] = {};
    if (q < 2) {
        #pragma unroll
        for (int h = 0; h < 2; ++h) {
            const float* p = Win + (size_t)(n0 + h * 16 + l16) * kIN + q * 32 + quad * 8;
            winfrag[h] = cvt8(*(const float4*)p, *(const float4*)(p + 4));
        }
    }

    // s staging geometry: 4 rounds x 512 threads x 8 halfs (16 B)
    const int srow0 = tid >> 5;            // 0..15, +16 per round
    const int sc8   = (tid & 31) * 8;      // col within chunk (halfs)
    const size_t sgbase = (size_t)(m0 + srow0) * kR + sc8;

    const int ldsA0 = ((2 * mh + 0) * 16 + l16) * SST;
    const int ldsA1 = ((2 * mh + 1) * 16 + l16) * SST;

    float* pf = (float*)ss;  // [4][64][PFS] fp32 partial scratch

    #pragma unroll 1
    for (int t = 0; t < kT; ++t) {
        // ---- X-frag raw loads for THIS step (hide L3 latency under spin) ----
        float4 xr[2][2];
        if (q < 2) {
            #pragma unroll
            for (int i = 0; i < 2; ++i) {
                const float* xp = X + ((size_t)(m0 + (2 * mh + i) * 16 + l16) * kT + t) * kIN
                                + q * 32 + quad * 8;
                xr[i][0] = *(const float4*)xp;
                xr[i][1] = *(const float4*)(xp + 4);
            }
        }

        f32x4 acc[2][2] = {};

        // ---- recurrent term over s_{t-1} ----
        if (t > 0) {
            const _Float16* sprev = (t & 1) ? sbuf0 : sbuf1;
            if (wave == 0) {
                if (lane == 0) {
                    const unsigned int need = (unsigned int)kBlocks * (unsigned int)t;
                    while (__hip_atomic_load(ctr, __ATOMIC_RELAXED, __HIP_MEMORY_SCOPE_AGENT) < need)
                        __builtin_amdgcn_s_sleep(2);
                }
                // ONE inv per block per step: drop stale s lines from L1/L2
                __builtin_amdgcn_fence(__ATOMIC_ACQUIRE, "agent");
            }
            __syncthreads();

            // preload chunk 0 (plain cached coalesced loads; L2 was invalidated)
            #pragma unroll
            for (int r = 0; r < 4; ++r) {
                f16x8 v = *(const f16x8*)(sprev + sgbase + (size_t)(16 * r) * kR);
                *(f16x8*)&ss[0][(srow0 + 16 * r) * SST + sc8] = v;
            }
            __syncthreads();

            #pragma unroll
            for (int c = 0; c < NCH; ++c) {
                f16x8 pre[4];
                if (c + 1 < NCH) {
                    #pragma unroll
                    for (int r = 0; r < 4; ++r)
                        pre[r] = *(const f16x8*)(sprev + sgbase + (size_t)(16 * r) * kR
                                                 + (c + 1) * CH);
                }
                const _Float16* buf = ss[c & 1];
                #pragma unroll
                for (int half = 0; half < 2; ++half) {
                    const int kloc = q * 32 + half * 128 + quad * 8;
                    f16x8 av0 = *(const f16x8*)&buf[ldsA0 + kloc];
                    f16x8 av1 = *(const f16x8*)&buf[ldsA1 + kloc];
                    acc[0][0] = MFMA16(av0, wfrag[0][2 * c + half], acc[0][0]);
                    acc[0][1] = MFMA16(av0, wfrag[1][2 * c + half], acc[0][1]);
                    acc[1][0] = MFMA16(av1, wfrag[0][2 * c + half], acc[1][0]);
                    acc[1][1] = MFMA16(av1, wfrag[1][2 * c + half], acc[1][1]);
                }
                if (c + 1 < NCH) {
                    _Float16* nbuf = ss[(c + 1) & 1];
                    #pragma unroll
                    for (int r = 0; r < 4; ++r)
                        *(f16x8*)&nbuf[(srow0 + 16 * r) * SST + sc8] = pre[r];
                }
                __syncthreads();
            }
        }

        // ---- input term (X loads issued at loop top are long done) ----
        if (q < 2) {
            #pragma unroll
            for (int i = 0; i < 2; ++i) {
                f16x8 a = cvt8(xr[i][0], xr[i][1]);
                acc[i][0] = MFMA16(a, winfrag[0], acc[i][0]);
                acc[i][1] = MFMA16(a, winfrag[1], acc[i][1]);
            }
        }

        // ---- reduce 4 k-phase partials through LDS, tanh, store ----
        #pragma unroll
        for (int i = 0; i < 2; ++i)
            #pragma unroll
            for (int h = 0; h < 2; ++h)
                #pragma unroll
                for (int r = 0; r < 4; ++r)
                    pf[q * 64 * PFS + (mh * 32 + i * 16 + quad * 4 + r) * PFS + h * 16 + l16]
                        = acc[i][h][r];
        __syncthreads();

        const int ml = tid >> 3, nl4 = (tid & 7) * 4;
        f32x4 v0 = *(const f32x4*)&pf[0 * 64 * PFS + ml * PFS + nl4];
        f32x4 v1 = *(const f32x4*)&pf[1 * 64 * PFS + ml * PFS + nl4];
        f32x4 v2 = *(const f32x4*)&pf[2 * 64 * PFS + ml * PFS + nl4];
        f32x4 v3 = *(const f32x4*)&pf[3 * 64 * PFS + ml * PFS + nl4];
        float o0 = tanhf(v0[0] + v1[0] + v2[0] + v3[0]);
        float o1 = tanhf(v0[1] + v1[1] + v2[1] + v3[1]);
        float o2 = tanhf(v0[2] + v1[2] + v2[2] + v3[2]);
        float o3 = tanhf(v0[3] + v1[3] + v2[3] + v3[3]);

        if (t < kT - 1) {
            _Float16* sout = (t & 1) ? sbuf1 : sbuf0;
            union { u64 u; _Float16 h[4]; } pk;
            pk.h[0] = (_Float16)o0; pk.h[1] = (_Float16)o1;
            pk.h[2] = (_Float16)o2; pk.h[3] = (_Float16)o3;
            // write-through to L3 (coherence point) — no wbl2 anywhere
            __hip_atomic_store((u64*)(sout + (size_t)(m0 + ml) * kR + n0 + nl4), pk.u,
                               __ATOMIC_RELAXED, __HIP_MEMORY_SCOPE_AGENT);
            __builtin_amdgcn_s_waitcnt(0);   // stores completed at L3
            __syncthreads();                 // whole block's stores completed
            if (tid == 0)
                __hip_atomic_fetch_add(ctr, 1u, __ATOMIC_RELAXED, __HIP_MEMORY_SCOPE_AGENT);
        } else {
            float4 o; o.x = o0; o.y = o1; o.z = o2; o.w = o3;
            *(float4*)(out + (size_t)(m0 + ml) * kR + n0 + nl4) = o;
        }
    }
}

extern "C" void kernel_launch(void* const* d_in, const int* in_sizes, int n_in,
                              void* d_out, int out_size, void* d_ws, size_t ws_size,
                              hipStream_t stream)
{
    const float* X   = (const float*)d_in[0];  // [B, T, IN]
    const float* Win = (const float*)d_in[1];  // [R, IN]
    const float* W   = (const float*)d_in[2];  // [R, R]
    float* out = (float*)d_out;                // [B, R]

    char* ws = (char*)d_ws;
    _Float16* s0 = (_Float16*)ws;                                  // 1 MB
    _Float16* s1 = (_Float16*)(ws + (size_t)kB * kR * 2);          // 1 MB
    unsigned int* ctr = (unsigned int*)(ws + 2 * (size_t)kB * kR * 2);

    hipMemsetAsync(ctr, 0, sizeof(unsigned int), stream);
    esn_persist<<<kBlocks, 512, 0, stream>>>(X, Win, W, out, s0, s1, ctr);
}

// Round 6
// 5419.569 us; speedup vs baseline: 6.3052x; 1.1922x over previous
//
#include <hip/hip_runtime.h>
#include <hip/hip_fp16.h>
#include <cmath>

// Problem constants (reference: B=256, T=512, IN=64, R=2048)
constexpr int kB  = 256;
constexpr int kT  = 512;
constexpr int kIN = 64;
constexpr int kR  = 2048;

constexpr int kBlocks = 256;   // 4 m-bands x 64 n-blocks -> 1 block/CU, all resident
constexpr int BN = 32;         // n per block (W-band in registers)
constexpr int BM = 64;         // batches per block
constexpr int CH  = 256;       // k per staged s-chunk (= 8 producer blocks' slices)
constexpr int NCH = kR / CH;   // 8 chunks = 8 flag groups
constexpr int SST = CH + 8;    // ss row stride (halfs) = 264
constexpr int PFS = 36;        // partial-scratch row stride (words)
constexpr int kNB = 64;        // n-blocks per m-band

typedef _Float16 f16x8 __attribute__((ext_vector_type(8)));
typedef float    f32x4 __attribute__((ext_vector_type(4)));
typedef unsigned long long u64;

#define MFMA16(a, b, c) __builtin_amdgcn_mfma_f32_16x16x32_f16((a), (b), (c), 0, 0, 0)

__device__ __forceinline__ f16x8 cvt8(float4 a, float4 b) {
    f16x8 v;
    v[0] = (_Float16)a.x; v[1] = (_Float16)a.y; v[2] = (_Float16)a.z; v[3] = (_Float16)a.w;
    v[4] = (_Float16)b.x; v[5] = (_Float16)b.y; v[6] = (_Float16)b.z; v[7] = (_Float16)b.w;
    return v;
}

// One coalesced poll of the band's 64 per-block flags (sc1 load, always fresh).
// Returns ballot mask: bit j set iff block j of the band has published step>=target.
__device__ __forceinline__ u64 poll_flags(const unsigned* f, int lane, unsigned target) {
    unsigned v = __hip_atomic_load(f + lane, __ATOMIC_RELAXED, __HIP_MEMORY_SCOPE_AGENT);
    return __ballot(v >= target);
}

// Persistent ESN: all 512 steps in one launch.
// Sync structure (r6): NO global barrier. Per-block flags (flag[m][nb] = last
// published step + 1). Each block's K-loop visits chunks in ring order starting
// at its OWN producer group (permutation baked into wfrag layout at W-load
// time, so register indices stay compile-time). The wait for chunk c+1's 8
// producers overlaps compute of chunk c; m-bands are fully decoupled.
// Coherence: producers publish via agent-scope u64 stores (write-through, no
// wbl2) + s_waitcnt + syncthreads + flag store; consumers do ONE acquire-inv
// per block per step after their first-group confirm (r5-proven pattern).
__global__ __launch_bounds__(512, 2) void esn_persist(
    const float* __restrict__ X,     // [B, T, IN]
    const float* __restrict__ Win,   // [R, IN]
    const float* __restrict__ W,     // [R, R]
    float* __restrict__ out,         // [B, R]
    _Float16* __restrict__ sbuf0,
    _Float16* __restrict__ sbuf1,
    unsigned* __restrict__ flags)    // [4][64], zeroed at launch
{
    // 2 x 33792 B = 67584 B; fp32 partial scratch [4][64][36] aliases it
    __shared__ __align__(16) _Float16 ss[2][64 * SST];

    const int tid  = threadIdx.x;
    const int wave = tid >> 6, lane = tid & 63;
    const int quad = lane >> 4, l16 = lane & 15;
    const int mh = wave >> 2;        // m-half: rows [mh*32, mh*32+32)
    const int q  = wave & 3;         // k-phase: kk ≡ q (mod 4)
    const int nb = blockIdx.x & 63;  // n-block within band
    const int mb = blockIdx.x >> 6;  // m-band
    const int n0 = nb * BN;
    const int m0 = mb * BM;
    const int c0 = nb >> 3;          // own flag group / ring start
    unsigned* bandflags = flags + mb * kNB;

    // ---- one-time: W-band -> register B-frags (f16), ring-permuted ----
    // Ring pos c maps to physical k-chunk p(c) = (c0+c)&7.
    // wfrag[h][2c+half] = W[n0+h*16+l16][kk*32 + quad*8 + j], kk = p(c)*8+half*4+q
    f16x8 wfrag[2][2 * NCH];
    #pragma unroll
    for (int h = 0; h < 2; ++h) {
        const float* wrow = W + (size_t)(n0 + h * 16 + l16) * kR;
        #pragma unroll
        for (int kki = 0; kki < 2 * NCH; ++kki) {
            const int kk = (((c0 + (kki >> 1)) & 7) << 3) + (kki & 1) * 4 + q;
            const float* p = wrow + kk * 32 + quad * 8;
            wfrag[h][kki] = cvt8(*(const float4*)p, *(const float4*)(p + 4));
        }
    }
    f16x8 winfrag[2] = {};
    if (q < 2) {
        #pragma unroll
        for (int h = 0; h < 2; ++h) {
            const float* p = Win + (size_t)(n0 + h * 16 + l16) * kIN + q * 32 + quad * 8;
            winfrag[h] = cvt8(*(const float4*)p, *(const float4*)(p + 4));
        }
    }

    // s staging geometry: 4 rounds x 512 threads x 8 halfs (16 B)
    const int srow0 = tid >> 5;            // 0..15, +16 per round
    const int sc8   = (tid & 31) * 8;      // col within chunk (halfs)
    const size_t sgbase = (size_t)(m0 + srow0) * kR + sc8;

    const int ldsA0 = ((2 * mh + 0) * 16 + l16) * SST;
    const int ldsA1 = ((2 * mh + 1) * 16 + l16) * SST;

    float* pf = (float*)ss;  // [4][64][PFS] fp32 partial scratch

    #pragma unroll 1
    for (int t = 0; t < kT; ++t) {
        // ---- X-frag raw loads for THIS step (latency hidden under sync) ----
        float4 xr[2][2];
        if (q < 2) {
            #pragma unroll
            for (int i = 0; i < 2; ++i) {
                const float* xp = X + ((size_t)(m0 + (2 * mh + i) * 16 + l16) * kT + t) * kIN
                                + q * 32 + quad * 8;
                xr[i][0] = *(const float4*)xp;
                xr[i][1] = *(const float4*)(xp + 4);
            }
        }

        f32x4 acc[2][2] = {};

        // ---- recurrent term over s_{t-1}, ring-ordered chunks ----
        if (t > 0) {
            const _Float16* sprev = (t & 1) ? sbuf0 : sbuf1;
            const unsigned target = (unsigned)t;   // flag >= t  <=>  s[t-1] published
            u64 fmask = 0;

            if (wave == 0) {
                fmask = poll_flags(bandflags, lane, target);
                while (((fmask >> (8 * c0)) & 0xffull) != 0xffull) {
                    __builtin_amdgcn_s_sleep(1);
                    fmask = poll_flags(bandflags, lane, target);
                }
                // ONE inv per block per step: drop stale s lines from L1/L2
                __builtin_amdgcn_fence(__ATOMIC_ACQUIRE, "agent");
            }
            __syncthreads();
            if (wave != 0) fmask = poll_flags(bandflags, lane, target);

            // preload ring-0 (own group: k-offset c0*CH)
            #pragma unroll
            for (int r = 0; r < 4; ++r) {
                f16x8 v = *(const f16x8*)(sprev + sgbase + (size_t)(16 * r) * kR + c0 * CH);
                *(f16x8*)&ss[0][(srow0 + 16 * r) * SST + sc8] = v;
            }
            __syncthreads();

            #pragma unroll
            for (int c = 0; c < NCH; ++c) {
                f16x8 pre[4];
                if (c + 1 < NCH) {
                    const int rg = (c0 + c + 1) & 7;       // physical chunk for ring pos c+1
                    while (((fmask >> (8 * rg)) & 0xffull) != 0xffull) {
                        __builtin_amdgcn_s_sleep(1);
                        fmask = poll_flags(bandflags, lane, target);
                    }
                    #pragma unroll
                    for (int r = 0; r < 4; ++r)
                        pre[r] = *(const f16x8*)(sprev + sgbase + (size_t)(16 * r) * kR
                                                 + rg * CH);
                }
                const _Float16* buf = ss[c & 1];
                #pragma unroll
                for (int half = 0; half < 2; ++half) {
                    const int kloc = q * 32 + half * 128 + quad * 8;
                    f16x8 av0 = *(const f16x8*)&buf[ldsA0 + kloc];
                    f16x8 av1 = *(const f16x8*)&buf[ldsA1 + kloc];
                    acc[0][0] = MFMA16(av0, wfrag[0][2 * c + half], acc[0][0]);
                    acc[0][1] = MFMA16(av0, wfrag[1][2 * c + half], acc[0][1]);
                    acc[1][0] = MFMA16(av1, wfrag[0][2 * c + half], acc[1][0]);
                    acc[1][1] = MFMA16(av1, wfrag[1][2 * c + half], acc[1][1]);
                }
                if (c + 1 < NCH) {
                    _Float16* nbuf = ss[(c + 1) & 1];
                    #pragma unroll
                    for (int r = 0; r < 4; ++r)
                        *(f16x8*)&nbuf[(srow0 + 16 * r) * SST + sc8] = pre[r];
                }
                __syncthreads();
            }
        }

        // ---- input term (X loads long done) ----
        if (q < 2) {
            #pragma unroll
            for (int i = 0; i < 2; ++i) {
                f16x8 a = cvt8(xr[i][0], xr[i][1]);
                acc[i][0] = MFMA16(a, winfrag[0], acc[i][0]);
                acc[i][1] = MFMA16(a, winfrag[1], acc[i][1]);
            }
        }

        // ---- reduce 4 k-phase partials through LDS, tanh, store ----
        #pragma unroll
        for (int i = 0; i < 2; ++i)
            #pragma unroll
            for (int h = 0; h < 2; ++h)
                #pragma unroll
                for (int r = 0; r < 4; ++r)
                    pf[q * 64 * PFS + (mh * 32 + i * 16 + quad * 4 + r) * PFS + h * 16 + l16]
                        = acc[i][h][r];
        __syncthreads();

        const int ml = tid >> 3, nl4 = (tid & 7) * 4;
        f32x4 v0 = *(const f32x4*)&pf[0 * 64 * PFS + ml * PFS + nl4];
        f32x4 v1 = *(const f32x4*)&pf[1 * 64 * PFS + ml * PFS + nl4];
        f32x4 v2 = *(const f32x4*)&pf[2 * 64 * PFS + ml * PFS + nl4];
        f32x4 v3 = *(const f32x4*)&pf[3 * 64 * PFS + ml * PFS + nl4];
        float o0 = tanhf(v0[0] + v1[0] + v2[0] + v3[0]);
        float o1 = tanhf(v0[1] + v1[1] + v2[1] + v3[1]);
        float o2 = tanhf(v0[2] + v1[2] + v2[2] + v3[2]);
        float o3 = tanhf(v0[3] + v1[3] + v2[3] + v3[3]);

        if (t < kT - 1) {
            _Float16* sout = (t & 1) ? sbuf1 : sbuf0;
            union { u64 u; _Float16 h[4]; } pk;
            pk.h[0] = (_Float16)o0; pk.h[1] = (_Float16)o1;
            pk.h[2] = (_Float16)o2; pk.h[3] = (_Float16)o3;
            // write-through to the coherence point — no wbl2 anywhere
            __hip_atomic_store((u64*)(sout + (size_t)(m0 + ml) * kR + n0 + nl4), pk.u,
                               __ATOMIC_RELAXED, __HIP_MEMORY_SCOPE_AGENT);
            __builtin_amdgcn_s_waitcnt(0);   // this thread's stores completed
            __syncthreads();                 // whole block's stores completed
            if (tid == 0)
                __hip_atomic_store(&bandflags[nb], (unsigned)(t + 1),
                                   __ATOMIC_RELAXED, __HIP_MEMORY_SCOPE_AGENT);
        } else {
            float4 o; o.x = o0; o.y = o1; o.z = o2; o.w = o3;
            *(float4*)(out + (size_t)(m0 + ml) * kR + n0 + nl4) = o;
        }
    }
}

extern "C" void kernel_launch(void* const* d_in, const int* in_sizes, int n_in,
                              void* d_out, int out_size, void* d_ws, size_t ws_size,
                              hipStream_t stream)
{
    const float* X   = (const float*)d_in[0];  // [B, T, IN]
    const float* Win = (const float*)d_in[1];  // [R, IN]
    const float* W   = (const float*)d_in[2];  // [R, R]
    float* out = (float*)d_out;                // [B, R]

    char* ws = (char*)d_ws;
    _Float16* s0 = (_Float16*)ws;                                  // 1 MB
    _Float16* s1 = (_Float16*)(ws + (size_t)kB * kR * 2);          // 1 MB
    unsigned* flags = (unsigned*)(ws + 2 * (size_t)kB * kR * 2);   // [4][64]

    hipMemsetAsync(flags, 0, 4 * kNB * sizeof(unsigned), stream);
    esn_persist<<<kBlocks, 512, 0, stream>>>(X, Win, W, out, s0, s1, flags);
}